// Round 8
// baseline (65.073 us; speedup 1.0000x reference)
//
#include <hip/hip_runtime.h>
#include <hip/hip_bf16.h>

// out[b,t,u,c] = enc[b,t,:]·W[c,:512] + dec[b,u,:]·W[c,512:]
// B=4, T=256, U=64, D=512, C=1024. Output 256 MiB fp32 (write floor ~40us).
//
// K1 cvt:   fp32 -> bf16 AND permute into MFMA-fragment order (coalesced
//           1 KB wave-loads in the GEMMs).
// K2 dec:   bf16-MFMA dec projection -> Pd (256x1024), fragment loads.
// K3 fused: per block (16 bt x 64 c): issue Pd loads first, enc MFMA tile
//           with 4-way split-K (4 serial k-steps/wave), ds_write decS after
//           the MFMA loop (Pd latency hides under GEMM), barrier, then
//           stream 256 KiB with nontemporal float4 stores.

typedef float v4f   __attribute__((ext_vector_type(4)));
typedef float f32x4 __attribute__((ext_vector_type(4)));
typedef __attribute__((ext_vector_type(8))) short short8;

__device__ inline short bf16_of(float f) {
    __hip_bfloat16 h = __float2bfloat16(f);   // RNE
    return *reinterpret_cast<short*>(&h);
}

// ---------------- K1: fp32 -> bf16 fragment-layout permute -------------------
// One wave per 16x32 fragment block (1 KiB out). Wave-task ids:
//   [0,1024)    : enc  (64 mb x 16 kb)
//   [1024,1280) : dec  (16 mb x 16 kb)
//   [1280,2304) : Wenc (64 cb x 16 kb), W cols [0,512)
//   [2304,3328) : Wdec (64 cb x 16 kb), W cols [512,1024)
__global__ __launch_bounds__(256) void cvt_frag(
    const float* __restrict__ enc, const float* __restrict__ dec,
    const float* __restrict__ W,
    ushort* __restrict__ Xe_f, ushort* __restrict__ Xd_f,
    ushort* __restrict__ We_f, ushort* __restrict__ Wd_f)
{
    const int tid  = threadIdx.x;
    const int lane = tid & 63;
    const int l16  = lane & 15;
    const int kq   = lane >> 4;
    const int gid  = blockIdx.x * 4 + (tid >> 6);

    const float* src; ushort* dst; int g, rowStride, colOfs;
    if (gid < 1024)      { src = enc; dst = Xe_f; g = gid;        rowStride = 512;  colOfs = 0;   }
    else if (gid < 1280) { src = dec; dst = Xd_f; g = gid - 1024; rowStride = 512;  colOfs = 0;   }
    else if (gid < 2304) { src = W;   dst = We_f; g = gid - 1280; rowStride = 1024; colOfs = 0;   }
    else                 { src = W;   dst = Wd_f; g = gid - 2304; rowStride = 1024; colOfs = 512; }

    const int rb  = g >> 4;       // 16-row block
    const int kbi = g & 15;       // 32-k block
    const float* p = src + (size_t)(rb * 16 + l16) * rowStride + colOfs + kbi * 32 + kq * 8;
    float4 lo = *(const float4*)p;
    float4 hi = *(const float4*)(p + 4);
    short8 o;
    o[0] = bf16_of(lo.x); o[1] = bf16_of(lo.y); o[2] = bf16_of(lo.z); o[3] = bf16_of(lo.w);
    o[4] = bf16_of(hi.x); o[5] = bf16_of(hi.y); o[6] = bf16_of(hi.z); o[7] = bf16_of(hi.w);
    *(short8*)&dst[(size_t)g * 512 + lane * 8] = o;
}

// ---------------- K2: dec projection GEMM (fragment loads, split-K) ----------
// Grid (16 c-tiles, 16 m-tiles); block tile = 16(m) x 64(c); 4 waves.
__global__ __launch_bounds__(256) void dec_gemm_bf16(
    const ushort* __restrict__ Xd_f,  // frag layout (16 mb x 16 kb)
    const ushort* __restrict__ Wd_f,  // frag layout (64 cb x 16 kb)
    float* __restrict__ Pd)           // (256, 1024)
{
    const int tid  = threadIdx.x;
    const int wave = tid >> 6;
    const int lane = tid & 63;
    const int l16  = lane & 15;
    const int kq   = lane >> 4;

    const int kz = wave >> 1;
    const int wn = (wave & 1) * 32;
    const int mb = blockIdx.y;
    const int cBase = blockIdx.x * 64;
    const int cb0 = blockIdx.x * 4 + (wave & 1) * 2;

    const short8* xa  = (const short8*)Xd_f + (size_t)(mb  * 16 + kz * 8) * 64 + lane;
    const short8* wb0 = (const short8*)Wd_f + (size_t)(cb0       * 16 + kz * 8) * 64 + lane;
    const short8* wb1 = (const short8*)Wd_f + (size_t)((cb0 + 1) * 16 + kz * 8) * 64 + lane;

    f32x4 acc0 = {0.f,0.f,0.f,0.f}, acc1 = {0.f,0.f,0.f,0.f};
#pragma unroll
    for (int s = 0; s < 8; ++s) {
        short8 a  = xa [(size_t)s * 64];
        short8 b0 = wb0[(size_t)s * 64];
        short8 b1 = wb1[(size_t)s * 64];
        acc0 = __builtin_amdgcn_mfma_f32_16x16x32_bf16(a, b0, acc0, 0, 0, 0);
        acc1 = __builtin_amdgcn_mfma_f32_16x16x32_bf16(a, b1, acc1, 0, 0, 0);
    }

    __shared__ float Ps[16][65];
    if (kz == 1) {
#pragma unroll
        for (int r = 0; r < 4; ++r) {
            Ps[kq * 4 + r][wn + l16]      = acc0[r];
            Ps[kq * 4 + r][wn + 16 + l16] = acc1[r];
        }
    }
    __syncthreads();
    if (kz == 0) {
        float* p0 = Pd + (size_t)(mb * 16) * 1024 + cBase + wn;
#pragma unroll
        for (int r = 0; r < 4; ++r) {
            const int row = kq * 4 + r;
            p0[(size_t)row * 1024 + l16]      = acc0[r] + Ps[row][wn + l16];
            p0[(size_t)row * 1024 + 16 + l16] = acc1[r] + Ps[row][wn + 16 + l16];
        }
    }
}

// ---------------- K3: fused enc GEMM + broadcast-add stream ------------------
// Grid (16 c-tiles, 64 bt-tiles), 256 threads = 4 waves.
// Wave kz = wave (K quarter); each wave covers all 64 c (4 B-frags).
__global__ __launch_bounds__(256) void fused_enc_stream(
    const ushort* __restrict__ Xe_f,  // frag layout (64 mb x 16 kb)
    const ushort* __restrict__ We_f,  // frag layout (64 cb x 16 kb)
    const float* __restrict__ Pd,     // (256, 1024)
    float* __restrict__ out)          // (1024, 64, 1024)
{
    const int tid  = threadIdx.x;
    const int kz   = tid >> 6;          // wave = K quarter
    const int lane = tid & 63;
    const int l16  = lane & 15;
    const int kq   = lane >> 4;

    const int btBase = blockIdx.y * 16;
    const int cBase  = blockIdx.x * 64;
    const int b      = blockIdx.y >> 4;

    __shared__ float encS[4][16][68];       // split-K partials (~17.4 KiB)
    __shared__ float decS[64][64];          // this block's Pd chunk (16 KiB)

    // (1) Issue Pd loads early; latency hides under the GEMM below.
    float4 v0, v1, v2, v3;
    {
        int s0 = tid;
        v0 = *(const float4*)&Pd[(size_t)(b * 64 + ((s0          ) >> 4)) * 1024 + cBase + ((s0          ) & 15) * 4];
        v1 = *(const float4*)&Pd[(size_t)(b * 64 + ((s0 + 256    ) >> 4)) * 1024 + cBase + ((s0 + 256    ) & 15) * 4];
        v2 = *(const float4*)&Pd[(size_t)(b * 64 + ((s0 + 512    ) >> 4)) * 1024 + cBase + ((s0 + 512    ) & 15) * 4];
        v3 = *(const float4*)&Pd[(size_t)(b * 64 + ((s0 + 768    ) >> 4)) * 1024 + cBase + ((s0 + 768    ) & 15) * 4];
    }

    // (2) Enc GEMM: 16 x 64 tile, 4-way split-K, 4 serial k-steps per wave.
    {
        const short8* xa = (const short8*)Xe_f + (size_t)(blockIdx.y * 16 + kz * 4) * 64 + lane;
        const short8* wb = (const short8*)We_f + (size_t)(kz * 4) * 64 + lane;
        f32x4 acc[4] = {{0.f,0.f,0.f,0.f},{0.f,0.f,0.f,0.f},{0.f,0.f,0.f,0.f},{0.f,0.f,0.f,0.f}};
#pragma unroll
        for (int s = 0; s < 4; ++s) {
            short8 a = xa[(size_t)s * 64];
#pragma unroll
            for (int j = 0; j < 4; ++j) {
                short8 bf = wb[((size_t)(blockIdx.x * 4 + j) * 16 + s) * 64];
                acc[j] = __builtin_amdgcn_mfma_f32_16x16x32_bf16(a, bf, acc[j], 0, 0, 0);
            }
        }
#pragma unroll
        for (int j = 0; j < 4; ++j)
#pragma unroll
            for (int r = 0; r < 4; ++r)      // D: col=l16, row=kq*4+r
                encS[kz][kq * 4 + r][j * 16 + l16] = acc[j][r];
    }

    // (3) Stage decS now (vmcnt waits land after the GEMM issued).
    {
        int s0 = tid;
        *(float4*)&decS[(s0          ) >> 4][((s0          ) & 15) * 4] = v0;
        *(float4*)&decS[(s0 + 256    ) >> 4][((s0 + 256    ) & 15) * 4] = v1;
        *(float4*)&decS[(s0 + 512    ) >> 4][((s0 + 512    ) & 15) * 4] = v2;
        *(float4*)&decS[(s0 + 768    ) >> 4][((s0 + 768    ) & 15) * 4] = v3;
    }

    __syncthreads();

    // (4) Stream: thread (row=tid>>4, slot=tid&15) -> out[btBase+row, u, cBase+slot*4].
    const int row = tid >> 4;
    const int c4  = (tid & 15) * 4;

    const float4 e0 = *(const float4*)&encS[0][row][c4];
    const float4 e1 = *(const float4*)&encS[1][row][c4];
    const float4 e2 = *(const float4*)&encS[2][row][c4];
    const float4 e3 = *(const float4*)&encS[3][row][c4];
    const v4f e = {e0.x + e1.x + e2.x + e3.x,
                   e0.y + e1.y + e2.y + e3.y,
                   e0.z + e1.z + e2.z + e3.z,
                   e0.w + e1.w + e2.w + e3.w};

    float* po = out + (size_t)(btBase + row) * 64 * 1024 + cBase + c4;

#pragma unroll 8
    for (int u = 0; u < 64; ++u) {
        float4 d = *(const float4*)&decS[u][c4];
        v4f r = {e.x + d.x, e.y + d.y, e.z + d.z, e.w + d.w};
        __builtin_nontemporal_store(r, (v4f*)&po[(size_t)u * 1024]);
    }
}

extern "C" void kernel_launch(void* const* d_in, const int* in_sizes, int n_in,
                              void* d_out, int out_size, void* d_ws, size_t ws_size,
                              hipStream_t stream) {
    const float* enc = (const float*)d_in[0];   // (4,256,512)
    const float* dec = (const float*)d_in[1];   // (4,64,512)
    const float* W   = (const float*)d_in[2];   // (1024,1024)
    float* out = (float*)d_out;

    // Workspace: Pd 1 MiB | Xe_f 1 MiB | Xd_f 256 KiB | We_f 1 MiB | Wd_f 1 MiB
    char* ws = (char*)d_ws;
    float*  Pd   = (float*)(ws);
    ushort* Xe_f = (ushort*)(ws + (1u << 20));
    ushort* Xd_f = (ushort*)(ws + (2u << 20));
    ushort* We_f = (ushort*)(ws + (2u << 20) + (1u << 18));
    ushort* Wd_f = (ushort*)(ws + (3u << 20) + (1u << 18));

    cvt_frag<<<dim3(832), 256, 0, stream>>>(enc, dec, W, Xe_f, Xd_f, We_f, Wd_f);
    dec_gemm_bf16<<<dim3(16, 16), 256, 0, stream>>>(Xd_f, Wd_f, Pd);
    fused_enc_stream<<<dim3(16, 64), 256, 0, stream>>>(Xe_f, We_f, Pd, out);
}